// Round 4
// baseline (36.544 us; speedup 1.0000x reference)
//
#include <hip/hip_runtime.h>

typedef unsigned int uint;

// Problem constants (from setup_inputs)
#define B_     2
#define C_     16
#define H_     66
#define W_     66
#define O_     64
#define CKK    144
#define NCH    36          // CKK/4
#define DIM    64          // output spatial
#define L_     4096        // DIM*DIM
#define N_     8192        // B_*L_
#define PLANE  524288      // N_*O_  (stride between (c,s) planes of rand_idx)
#define TROWS  61          // table rows 0..60 (0..7 zeroed: sign(Q)==0 there)
#define TCOLS  1000

typedef _Float16 h4 __attribute__((ext_vector_type(4)));

// ---- prefetch group: 4 chunks x 2 signs, int2 per lane (o-pair) -----------
__device__ __forceinline__ void loadg(int2 (&buf)[8],
                                      const int* __restrict__ rp, int c0) {
#pragma unroll
    for (int j = 0; j < 4; ++j) {
        int c = c0 + j;
        buf[2 * j + 0] = *(const int2*)(rp + (2 * c)     * PLANE);
        buf[2 * j + 1] = *(const int2*)(rp + (2 * c + 1) * PLANE);
    }
}

// ---- consume one group: dot4 masks + 4 unconditional LDS gathers per j ----
__device__ __forceinline__ void procg(const int2 (&buf)[8],
                                      const uint*  __restrict__ xqp,  // &s_xq[s][n_local*NCH]
                                      const uint4* __restrict__ swp,  // &s_w4[p]
                                      const _Float16* __restrict__ tbl,
                                      int c0, float& sum0, float& sum1) {
#pragma unroll
    for (int j = 0; j < 4; ++j) {
        int c = c0 + j;
        uint  xv = xqp[c];                  // wave-broadcast (2 addrs/wave)
        uint4 m  = swp[c * 32];             // ds_read_b128, conflict-free
        uint yp0 = ((xv & m.x) * 0x01010101u) >> 24;
        uint ym0 = ((xv & m.y) * 0x01010101u) >> 24;
        uint yp1 = ((xv & m.z) * 0x01010101u) >> 24;
        uint ym1 = ((xv & m.w) * 0x01010101u) >> 24;
        int2 b0 = buf[2 * j + 0];           // indices (o0,o1), sign +
        int2 b1 = buf[2 * j + 1];           // indices (o0,o1), sign -
        sum0 += (float)tbl[yp0 * TCOLS + b0.x];
        sum0 -= (float)tbl[ym0 * TCOLS + b1.x];
        sum1 += (float)tbl[yp1 * TCOLS + b0.y];
        sum1 -= (float)tbl[ym1 * TCOLS + b1.y];
    }
}

__launch_bounds__(1024)
__global__ void k_fused(const float* __restrict__ x,
                        const float* __restrict__ wgt,
                        const float* __restrict__ cbias,
                        const float* __restrict__ pmin,
                        const float* __restrict__ pmax,
                        const float* __restrict__ ptbl,
                        const int*   __restrict__ ridx,
                        float* __restrict__ out) {
    __shared__ __align__(16) _Float16 tbl[TROWS * TCOLS]; // 122,000 B
    __shared__ uint4 s_w4[NCH * 32];                      //  18,432 B (o-pair packed)
    __shared__ float s_bias[O_];                          //     256 B
    __shared__ uint  s_xq[2][16 * NCH];                   //   4,608 B

    const int tid  = threadIdx.x;
    const int wv   = tid >> 6;
    const int lane = tid & 63;
    const int p    = lane & 31;            // o-pair: o0=2p, o1=2p+1
    const int h    = lane >> 5;            // which n of this wave's pair
    const int s    = wv >> 3;              // stream: 0 = batch0, 1 = batch1
    const int nloc = 2 * (wv & 7) + h;     // 0..15 within tile
    const int o0   = 2 * p;

    const float mn = pmin[0];
    const float sc = pmax[0] - mn;

    // ---- issue 4-deep index prefetch FIRST (oldest in vmcnt queue) ----
    const int n_g = blockIdx.x * 16 + nloc + s * 4096;    // global n
    const int* rp = ridx + n_g * O_ + o0;
    int2 A[8], Bb[8], Cc[8], Dd[8];
    loadg(A,  rp, 0);
    loadg(Bb, rp, 4);
    loadg(Cc, rp, 8);
    loadg(Dd, rp, 12);

    // ---- Phase 0a: zero rows 0..7 (16,000 B) ----
    {
        uint4 z; z.x = z.y = z.z = z.w = 0u;
        uint4* zp = (uint4*)tbl;
        for (int q = tid; q < 1000; q += 1024) zp[q] = z;
    }
    // ---- Phase 0b: rows 8..60 -> fp16 LDS, float4-vectorized ----
    {
        const float4* src = (const float4*)(ptbl + 8 * TCOLS);
        h4* dst = (h4*)(tbl + 8 * TCOLS);
        for (int q = tid; q < (53 * TCOLS) / 4; q += 1024) {
            float4 v = src[q];
            h4 hh = { (_Float16)v.x, (_Float16)v.y, (_Float16)v.z, (_Float16)v.w };
            dst[q] = hh;
        }
    }
    // ---- Phase 0c: ternary weight byte-masks, o-pair packed ----
    for (int q = tid; q < NCH * 32; q += 1024) {
        int c = q >> 5, pp = q & 31;
        uint4 mo;
        float4 v0 = *(const float4*)(wgt + (2 * pp)     * CKK + c * 4);
        float4 v1 = *(const float4*)(wgt + (2 * pp + 1) * CKK + c * 4);
        uint pm = 0, nm = 0;
        if (v0.x > 0.0f) pm |= 0x000000FFu; else if (v0.x < 0.0f) nm |= 0x000000FFu;
        if (v0.y > 0.0f) pm |= 0x0000FF00u; else if (v0.y < 0.0f) nm |= 0x0000FF00u;
        if (v0.z > 0.0f) pm |= 0x00FF0000u; else if (v0.z < 0.0f) nm |= 0x00FF0000u;
        if (v0.w > 0.0f) pm |= 0xFF000000u; else if (v0.w < 0.0f) nm |= 0xFF000000u;
        mo.x = pm; mo.y = nm;
        pm = 0; nm = 0;
        if (v1.x > 0.0f) pm |= 0x000000FFu; else if (v1.x < 0.0f) nm |= 0x000000FFu;
        if (v1.y > 0.0f) pm |= 0x0000FF00u; else if (v1.y < 0.0f) nm |= 0x0000FF00u;
        if (v1.z > 0.0f) pm |= 0x00FF0000u; else if (v1.z < 0.0f) nm |= 0x00FF0000u;
        if (v1.w > 0.0f) pm |= 0xFF000000u; else if (v1.w < 0.0f) nm |= 0xFF000000u;
        mo.z = pm; mo.w = nm;
        s_w4[c * 32 + pp] = mo;
    }
    // ---- Phase 0d: quantize both tiles' 32 patches into s_xq ----
    for (int i = tid; i < 2 * 16 * NCH; i += 1024) {
        int t  = i / (16 * NCH);
        int r  = i - t * (16 * NCH);
        int nl2 = r / NCH;
        int c2  = r - nl2 * NCH;
        int n2  = blockIdx.x * 16 + nl2 + t * 4096;
        int b2 = n2 >> 12, l2 = n2 & (L_ - 1);
        int h2 = l2 >> 6,  w2 = l2 & (DIM - 1);
        uint packed = 0;
#pragma unroll
        for (int k = 0; k < 4; ++k) {
            int j  = c2 * 4 + k;
            int ci = j / 9;
            int r2 = j - ci * 9;
            int kh = r2 / 3;
            int kw = r2 - kh * 3;
            float v = x[((b2 * C_ + ci) * H_ + (h2 + kh)) * W_ + (w2 + kw)];
            float t2 = (v - mn) / sc * 15.0f;                  // jax f32 op order
            float q = fminf(fmaxf(rintf(t2), 0.0f), 15.0f);
            packed |= ((uint)q) << (8 * k);
        }
        s_xq[t][r] = packed;
    }
    __syncthreads();

    // ---- bias from masks (threads 0..31, one o-pair each) ----
    if (tid < 32) {
        int sw0 = 0, sw1 = 0;
        for (int c = 0; c < NCH; ++c) {
            uint4 m = s_w4[c * 32 + tid];
            sw0 += (__popc(m.x) >> 3) - (__popc(m.y) >> 3);
            sw1 += (__popc(m.z) >> 3) - (__popc(m.w) >> 3);
        }
        s_bias[2 * tid]     = mn * (float)sw0 + cbias[2 * tid];
        s_bias[2 * tid + 1] = mn * (float)sw1 + cbias[2 * tid + 1];
    }
    __syncthreads();

    // ---- main: 4-deep software pipeline over 9 groups ----
    const uint*  xqp = &s_xq[s][nloc * NCH];
    const uint4* swp = &s_w4[p];
    float sum0 = 0.0f, sum1 = 0.0f;

    procg(A,  xqp, swp, tbl,  0, sum0, sum1); loadg(A,  rp, 16);
    procg(Bb, xqp, swp, tbl,  4, sum0, sum1); loadg(Bb, rp, 20);
    procg(Cc, xqp, swp, tbl,  8, sum0, sum1); loadg(Cc, rp, 24);
    procg(Dd, xqp, swp, tbl, 12, sum0, sum1); loadg(Dd, rp, 28);
    procg(A,  xqp, swp, tbl, 16, sum0, sum1); loadg(A,  rp, 32);
    procg(Bb, xqp, swp, tbl, 20, sum0, sum1);
    procg(Cc, xqp, swp, tbl, 24, sum0, sum1);
    procg(Dd, xqp, swp, tbl, 28, sum0, sum1);
    procg(A,  xqp, swp, tbl, 32, sum0, sum1);

    // ---- store: out[b][o][l], b = s, l = bid*16 + nloc ----
    const int l = blockIdx.x * 16 + nloc;
    out[(s * O_ + o0)     * L_ + l] = sum0 * sc + s_bias[o0];
    out[(s * O_ + o0 + 1) * L_ + l] = sum1 * sc + s_bias[o0 + 1];
}

extern "C" void kernel_launch(void* const* d_in, const int* in_sizes, int n_in,
                              void* d_out, int out_size, void* d_ws, size_t ws_size,
                              hipStream_t stream) {
    const float* x     = (const float*)d_in[0];
    const float* wgt   = (const float*)d_in[1];
    const float* cbias = (const float*)d_in[2];
    const float* pmin  = (const float*)d_in[3];
    const float* pmax  = (const float*)d_in[4];
    const float* ptbl  = (const float*)d_in[5];
    const int*   ridx  = (const int*)d_in[6];
    float* out = (float*)d_out;

    k_fused<<<256, 1024, 0, stream>>>(x, wgt, cbias, pmin, pmax, ptbl, ridx, out);
}